// Round 9
// baseline (369.759 us; speedup 1.0000x reference)
//
#include <hip/hip_runtime.h>
#include <stdint.h>

#define QN    300
#define WN    10
#define CD    640
#define IJ    196
#define MROWS 1960              // WN*IJ
#define NTOT  58800             // QN*IJ
#define OUTQ  384160            // MROWS*IJ
#define EPSV  1e-8f

#define BM    256
#define BN    128
#define BK    32
#define BUFE  ((BM + BN) * BK)         // 12288 ushorts = 24 KB per buffer
#define NTK   (CD / BK)                // 20 K-tiles

#define MT_TILES 8                     // m tiles of 256 (pad 2048)
#define NT_TILES 460                   // n tiles of 128 (pad 58880)
#define NWG      (MT_TILES * NT_TILES) // 3680, divisible by 8
#define CPX      (NWG / 8)             // 460

typedef __attribute__((ext_vector_type(8))) short bf16x8;
typedef __attribute__((ext_vector_type(4))) float f32x4;

__device__ __forceinline__ unsigned short f2bf(float f) {
    uint32_t u = __float_as_uint(f);
    u += 0x7FFFu + ((u >> 16) & 1u);   // RNE
    return (unsigned short)(u >> 16);
}

__device__ __forceinline__ void gload16(const void* g, void* l) {
    __builtin_amdgcn_global_load_lds(
        (const __attribute__((address_space(1))) void*)g,
        (__attribute__((address_space(3))) void*)l,
        16, 0, 0);
}

// ---------------------------------------------------------------------------
// Pre-pass: X[B][640][196] fp32 -> XT[B*196][640] bf16 (k contiguous), with
// a 2-bit swizzle baked per 16B unit within each 4-unit (32-elem) K-group:
// stored_unit = (u&~3) | ((u&3) ^ ((row>>1)&3)).   (BK=32 rows are 64 B; key
// (row>>1)&3 + the natural row-parity bit spreads a wave's 64 frag-lanes
// across all 8 16B-slots of the 128B bank cycle at 2 lanes/slot = free.)
// Also fp32 norms.
// ---------------------------------------------------------------------------
__global__ __launch_bounds__(256)
void prep_kernel(const float* __restrict__ X, uint4* __restrict__ XT,
                 float* __restrict__ nrm)
{
    __shared__ float T[128][21];
    __shared__ float ssL[16][17];

    const int b  = blockIdx.y;
    const int i0 = blockIdx.x * 16;
    const int t  = threadIdx.x;
    const float* Xb = X + (size_t)b * (CD * IJ);

    const int cA  = t >> 2;              // 0..63
    const int i4  = (t & 3) * 4;         // 0,4,8,12
    const int iv  = i0 + i4;
    const bool liv = (iv <= IJ - 4);

    const int il = t >> 4;               // 0..15
    const int u  = t & 15;               // 0..15
    float ss = 0.f;

    const int ig   = i0 + il;
    const bool wok = (ig < IJ);
    const int rowg = b * IJ + (wok ? ig : IJ - 1);
    const int uxor = (rowg >> 1) & 3;    // 2-bit swizzle key (BK=32 groups)

    for (int cc = 0; cc < CD / 128; ++cc) {
        #pragma unroll
        for (int pass = 0; pass < 2; ++pass) {
            int cl = pass * 64 + cA;
            int c  = cc * 128 + cl;
            float4 v = make_float4(0.f, 0.f, 0.f, 0.f);
            if (liv) v = *(const float4*)&Xb[(size_t)c * IJ + iv];
            T[cl][i4 + 0] = v.x; T[cl][i4 + 1] = v.y;
            T[cl][i4 + 2] = v.z; T[cl][i4 + 3] = v.w;
        }
        __syncthreads();
        float v[8];
        #pragma unroll
        for (int r = 0; r < 8; ++r) { v[r] = T[u * 8 + r][il]; ss += v[r] * v[r]; }
        if (wok) {
            union { unsigned short s[8]; uint4 q; } pk;
            #pragma unroll
            for (int r = 0; r < 8; ++r) pk.s[r] = f2bf(v[r]);
            int us = (u & 12) | ((u & 3) ^ uxor);
            XT[(size_t)rowg * (CD / 8) + cc * 16 + us] = pk.q;
        }
        __syncthreads();
    }

    ssL[il][u] = ss;
    __syncthreads();
    if (t < 16) {
        int igw = i0 + t;
        if (igw < IJ) {
            float s = 0.f;
            #pragma unroll
            for (int k = 0; k < 16; ++k) s += ssL[t][k];
            nrm[b * IJ + igw] = sqrtf(s);
        }
    }
}

// ---------------------------------------------------------------------------
// GEMM: C[m][n] = sum_c AT[m][c]*BT[n][c].  256x128 tile, BK=32, 8 waves
// (4M x 2N), wave tile 64x64 (acc[4][4] of 16x16x32), 2 BLOCKS/CU
// (72 KB LDS/block, <=128 VGPR target via __launch_bounds__(512,4)).
//
// 3-deep circular LDS pipeline, 1 phase per K-tile (20 phases):
//   { ST(t+2): 3 gload16 | rd 8 frags(t) | lgkm0 | 16 MFMA (setprio) |
//     VMC(3) | bar }
// Counted-vmcnt audit: 3 loads/wave/phase; at each VMC(3) the oldest 3
// (tile t+1's stage, issued last phase) are landed, tile t+2's 3 in flight
// -> never drains to 0.  Buffer hazards: phase t+1 stages into buf[t%3],
// whose last ds_reads completed before phase t's trailing barrier.  Tail
// stages (tiles 20,21) read benign in-ws OOB, land in dead LDS, drained by
// the final VMC(0).  Swapped-operand MFMA -> float4 epilogue stores.
// Fragment offsets are loop-invariant; buffer offset is a compile-time
// immediate (3-unrolled phase sequence).
// ---------------------------------------------------------------------------
__global__ __launch_bounds__(512, 4)
void gemm_kernel(const uint4* __restrict__ AT, const uint4* __restrict__ BT,
                 const float* __restrict__ pn, const float* __restrict__ qn,
                 float* __restrict__ out)
{
    __shared__ unsigned short lds[3 * BUFE];   // 72 KB

    const int bid = blockIdx.x;
    const int swz = (bid & 7) * CPX + (bid >> 3);   // bijective (3680%8==0)
    const int mt  = swz & (MT_TILES - 1);
    const int nt  = swz >> 3;
    const int m0  = mt * BM;
    const int n0  = nt * BN;

    const int t  = threadIdx.x;
    const int w  = t >> 6, l = t & 63;
    const int fr = l & 15, fq = l >> 4;
    const int wm0 = (w >> 1) * 64;    // 4 M-waves
    const int wn0 = (w & 1) * 64;     // 2 N-waves

    // ---- staging: per phase each wave issues 3 gload16 (A:2, B:1).
    // instruction covers 16 rows (lane: row = l>>2, unit = l&3).
    const int lr = l >> 2, lu = l & 3;
    int ra0 = m0 +       w * 16 + lr;                      // < 1960 always
    int ra1 = m0 + 128 + w * 16 + lr; if (ra1 > MROWS - 1) ra1 = MROWS - 1;
    int rb  = n0 +       w * 16 + lr; if (rb  > NTOT  - 1) rb  = NTOT  - 1;
    const uint4* ga0 = AT + (size_t)ra0 * 80 + lu;
    const uint4* ga1 = AT + (size_t)ra1 * 80 + lu;
    const uint4* gb  = BT + (size_t)rb  * 80 + lu;
    // wave-uniform LDS elem bases (HW adds lane*16B)
    const int wA0 = (      w * 16) * BK;
    const int wA1 = (128 + w * 16) * BK;
    const int wB  = BM * BK + (w * 16) * BK;

    // ---- fragment read offsets: fully loop-invariant (incl. swizzle + fq)
    const int fqS = fq << 3;
    int foA[4], foB[4];
    #pragma unroll
    for (int i = 0; i < 4; ++i) {
        int rowa = wm0 + i * 16 + fr;
        foA[i] = rowa * BK + (fqS ^ ((((rowa) >> 1) & 3) << 3));
        int rowb = wn0 + i * 16 + fr;
        foB[i] = BM * BK + rowb * BK + (fqS ^ ((((rowb) >> 1) & 3) << 3));
    }

    f32x4 acc[4][4];
    #pragma unroll
    for (int a = 0; a < 4; ++a)
        #pragma unroll
        for (int bb = 0; bb < 4; ++bb)
            acc[a][bb] = (f32x4){0.f, 0.f, 0.f, 0.f};

#define ST3(OS)                                                           \
    gload16(ga0, (char*)&lds[(OS) + wA0]); ga0 += 4;                      \
    gload16(ga1, (char*)&lds[(OS) + wA1]); ga1 += 4;                      \
    gload16(gb,  (char*)&lds[(OS) + wB ]); gb  += 4;

#define BAR    __builtin_amdgcn_s_barrier()
#define LGKM0  do { asm volatile("s_waitcnt lgkmcnt(0)" ::: "memory");    \
                    __builtin_amdgcn_sched_barrier(0); } while (0)
#define VMC(N) asm volatile("s_waitcnt vmcnt(" #N ")" ::: "memory")
#define PRIO1  __builtin_amdgcn_s_setprio(1)
#define PRIO0  __builtin_amdgcn_s_setprio(0)

#define PHASE(OC, OS)                                                     \
  { bf16x8 af[4], bfv[4];                                                 \
    ST3(OS);                                                              \
    _Pragma("unroll")                                                     \
    for (int mm = 0; mm < 4; ++mm)                                        \
        af[mm]  = *(const bf16x8*)&lds[(OC) + foA[mm]];                   \
    _Pragma("unroll")                                                     \
    for (int nn = 0; nn < 4; ++nn)                                        \
        bfv[nn] = *(const bf16x8*)&lds[(OC) + foB[nn]];                   \
    LGKM0;                                                                \
    PRIO1;                                                                \
    _Pragma("unroll")                                                     \
    for (int mm = 0; mm < 4; ++mm)                                        \
        _Pragma("unroll")                                                 \
        for (int nn = 0; nn < 4; ++nn)                                    \
            acc[mm][nn] = __builtin_amdgcn_mfma_f32_16x16x32_bf16(        \
                bfv[nn], af[mm], acc[mm][nn], 0, 0, 0);                   \
    PRIO0;                                                                \
    VMC(3); BAR; }

    // ---- prologue: stage tiles 0,1; VMC(3) -> tile0 landed, tile1 in flight
    ST3(0); ST3(BUFE);
    VMC(3); BAR;

    // ---- 20 phases, 3-unrolled so LDS offsets are immediates
    for (int i5 = 0; i5 < 6; ++i5) {
        PHASE(0 * BUFE, 2 * BUFE)
        PHASE(1 * BUFE, 0 * BUFE)
        PHASE(2 * BUFE, 1 * BUFE)
    }
    PHASE(0 * BUFE, 2 * BUFE)
    PHASE(1 * BUFE, 0 * BUFE)

    VMC(0);   // drain tail garbage stages before epilogue

#undef PHASE
#undef ST3
#undef BAR
#undef LGKM0
#undef VMC
#undef PRIO1
#undef PRIO0

    // ---- epilogue (swapped D-layout): m = col (fr), n rows (fq*4+e)
    //   m = m0 + wm0 + tm*16 + fr
    //   n = n0 + wn0 + tn*16 + fq*4 + e   (e=0..3 consecutive -> float4)
    // 196%4==0 and 58800%4==0 => aligned quads never cross a q row.
    float4 rqv4[4];
    int    nok[4];
    size_t ob[4];
    #pragma unroll
    for (int tn = 0; tn < 4; ++tn) {
        int n = n0 + wn0 + tn * 16 + fq * 4;
        nok[tn] = (n < NTOT);
        int nc = nok[tn] ? n : NTOT - 4;
        int q  = nc / IJ;
        int j  = nc - q * IJ;
        rqv4[tn] = *(const float4*)&qn[nc];
        ob[tn] = (size_t)q * OUTQ + j;
    }
    #pragma unroll
    for (int tm = 0; tm < 4; ++tm) {
        int m = m0 + wm0 + tm * 16 + fr;
        if (m < MROWS) {
            float rp = pn[m];
            #pragma unroll
            for (int tn = 0; tn < 4; ++tn) {
                if (nok[tn]) {
                    f32x4 a = acc[tm][tn];
                    float4 o;
                    o.x = a[0] * __builtin_amdgcn_rcpf(fmaxf(rp * rqv4[tn].x, EPSV));
                    o.y = a[1] * __builtin_amdgcn_rcpf(fmaxf(rp * rqv4[tn].y, EPSV));
                    o.z = a[2] * __builtin_amdgcn_rcpf(fmaxf(rp * rqv4[tn].z, EPSV));
                    o.w = a[3] * __builtin_amdgcn_rcpf(fmaxf(rp * rqv4[tn].w, EPSV));
                    *(float4*)&out[ob[tn] + (size_t)m * IJ] = o;
                }
            }
        }
    }
}

// ---------------------------------------------------------------------------
// Fallback (round-1 kernel, known-passing) if ws_size is insufficient.
// ---------------------------------------------------------------------------
#define BMF 128
#define BNF 224
#define LPAD 40
__global__ __launch_bounds__(512, 4)
void sim_fallback(const float* __restrict__ proto,
                  const float* __restrict__ query,
                  float* __restrict__ out)
{
    __shared__ unsigned short As[BMF][LPAD];
    __shared__ unsigned short Bs[BNF][LPAD];
    __shared__ float redA[4][BMF];
    __shared__ float redB[2][BNF];
    __shared__ float rpS[BMF];
    __shared__ float rqS[BNF];

    const int tid = threadIdx.x;
    const int m0  = blockIdx.x * BMF;
    const int q   = blockIdx.y;

    const int mA  = tid & (BMF - 1);
    const int krA = tid >> 7;
    const int wiA = m0 + mA;
    const bool va = (wiA < MROWS);
    const int wA  = va ? (wiA / IJ) : 0;
    const int iA  = va ? (wiA - wA * IJ) : 0;
    const float* pA = proto + wA * (CD * IJ) + iA;

    const bool tb  = (tid < 448);
    const int jB   = tb ? (tid % BNF) : 0;
    const int krB  = tb ? (tid / BNF) : 0;
    const bool vb  = tb && (jB < IJ);
    const float* qB = query + q * (CD * IJ) + jB;

    float ssA = 0.f, ssB = 0.f;

    const int wv   = tid >> 6;
    const int lane = tid & 63;
    const int wm0  = (wv >> 1) * 32;
    const int wn0  = (wv & 1) * 112;
    const int fr   = lane & 15;
    const int fq   = lane >> 4;

    f32x4 acc[2][7];
    #pragma unroll
    for (int a = 0; a < 2; a++)
        #pragma unroll
        for (int b = 0; b < 7; b++)
            acc[a][b] = (f32x4){0.f, 0.f, 0.f, 0.f};

    for (int it = 0; it < CD / 32; ++it) {
        const int c0 = it * 32;
        {
            float v[8];
            #pragma unroll
            for (int e = 0; e < 8; e++) {
                int c = c0 + krA * 8 + e;
                v[e] = va ? pA[c * IJ] : 0.f;
            }
            #pragma unroll
            for (int e = 0; e < 8; e++) ssA += v[e] * v[e];
            union { unsigned short s[8]; uint4 u; } pk;
            #pragma unroll
            for (int e = 0; e < 8; e++) pk.s[e] = f2bf(v[e]);
            *(uint4*)&As[mA][krA * 8] = pk.u;
        }
        if (tb) {
            #pragma unroll
            for (int h = 0; h < 2; ++h) {
                float v[8];
                #pragma unroll
                for (int e = 0; e < 8; e++) {
                    int c = c0 + krB * 16 + h * 8 + e;
                    v[e] = vb ? qB[c * IJ] : 0.f;
                }
                #pragma unroll
                for (int e = 0; e < 8; e++) ssB += v[e] * v[e];
                union { unsigned short s[8]; uint4 u; } pk;
                #pragma unroll
                for (int e = 0; e < 8; e++) pk.s[e] = f2bf(v[e]);
                *(uint4*)&Bs[jB][krB * 16 + h * 8] = pk.u;
            }
        }
        __syncthreads();
        bf16x8 af[2], bfv[7];
        #pragma unroll
        for (int tm = 0; tm < 2; tm++)
            af[tm] = *(const bf16x8*)&As[wm0 + tm * 16 + fr][fq * 8];
        #pragma unroll
        for (int tn = 0; tn < 7; tn++)
            bfv[tn] = *(const bf16x8*)&Bs[wn0 + tn * 16 + fr][fq * 8];
        #pragma unroll
        for (int tm = 0; tm < 2; tm++)
            #pragma unroll
            for (int tn = 0; tn < 7; tn++)
                acc[tm][tn] = __builtin_amdgcn_mfma_f32_16x16x32_bf16(
                    af[tm], bfv[tn], acc[tm][tn], 0, 0, 0);
        __syncthreads();
    }

    redA[krA][mA] = ssA;
    if (tb) redB[krB][jB] = ssB;
    __syncthreads();
    if (tid < BMF) {
        rpS[tid] = sqrtf(redA[0][tid] + redA[1][tid] + redA[2][tid] + redA[3][tid]);
    } else if (tid >= 256 && tid < 256 + BNF) {
        int j = tid - 256;
        rqS[j] = sqrtf(redB[0][j] + redB[1][j]);
    }
    __syncthreads();

    #pragma unroll
    for (int tm = 0; tm < 2; tm++) {
        #pragma unroll
        for (int tn = 0; tn < 7; tn++) {
            #pragma unroll
            for (int r = 0; r < 4; r++) {
                int rl = wm0 + tm * 16 + fq * 4 + r;
                int cl = wn0 + tn * 16 + fr;
                int wi = m0 + rl;
                if (wi < MROWS && cl < IJ) {
                    float denom = fmaxf(rpS[rl] * rqS[cl], 1e-8f);
                    out[(size_t)(q * MROWS + wi) * IJ + cl] = acc[tm][tn][r] / denom;
                }
            }
        }
    }
}

// ---------------------------------------------------------------------------
extern "C" void kernel_launch(void* const* d_in, const int* in_sizes, int n_in,
                              void* d_out, int out_size, void* d_ws, size_t ws_size,
                              hipStream_t stream) {
    const float* proto = (const float*)d_in[0];
    const float* query = (const float*)d_in[1];
    float* out = (float*)d_out;

    // workspace layout
    const size_t off_pT = 0;                       // 1960*640*2 = 2,508,800
    const size_t off_qT = 2508800;                 // 58800*640*2 = 75,264,000
    const size_t off_pn = 77772800;                // 1960*4
    const size_t off_qn = 77780736;                // 58800*4
    const size_t need   = 78015936;

    if (ws_size < need) {
        dim3 grid((MROWS + BMF - 1) / BMF, QN);
        sim_fallback<<<grid, 512, 0, stream>>>(proto, query, out);
        return;
    }

    char* ws = (char*)d_ws;
    uint4* pT = (uint4*)(ws + off_pT);
    uint4* qT = (uint4*)(ws + off_qT);
    float* pn = (float*)(ws + off_pn);
    float* qn = (float*)(ws + off_qn);

    prep_kernel<<<dim3(13, QN), 256, 0, stream>>>(query, qT, qn);
    prep_kernel<<<dim3(13, WN), 256, 0, stream>>>(proto, pT, pn);

    gemm_kernel<<<dim3(NWG), 512, 0, stream>>>(pT, qT, pn, qn, out);
}

// Round 10
// 353.709 us; speedup vs baseline: 1.0454x; 1.0454x over previous
//
#include <hip/hip_runtime.h>
#include <stdint.h>

#define QN    300
#define WN    10
#define CD    640
#define IJ    196
#define MROWS 1960              // WN*IJ
#define NTOT  58800             // QN*IJ
#define OUTQ  384160            // MROWS*IJ
#define EPSV  1e-8f

#define BM    256
#define BN    256
#define BK    64
#define BUFE  ((BM + BN) * BK)         // 32768 ushorts = 64 KB per buffer
#define NTK   (CD / BK)                // 10 K-tiles

#define MT_TILES 8                     // m tiles of 256 (pad 2048)
#define NT_TILES 230                   // n tiles of 256 (pad 58880)
#define NWG      (MT_TILES * NT_TILES) // 1840, divisible by 8
#define CPX      (NWG / 8)             // 230

typedef __attribute__((ext_vector_type(8))) short bf16x8;
typedef __attribute__((ext_vector_type(4))) float f32x4;

__device__ __forceinline__ unsigned short f2bf(float f) {
    uint32_t u = __float_as_uint(f);
    u += 0x7FFFu + ((u >> 16) & 1u);   // RNE
    return (unsigned short)(u >> 16);
}

__device__ __forceinline__ void gload16(const void* g, void* l) {
    __builtin_amdgcn_global_load_lds(
        (const __attribute__((address_space(1))) void*)g,
        (__attribute__((address_space(3))) void*)l,
        16, 0, 0);
}

// ---------------------------------------------------------------------------
// Combined pre-pass (ONE launch for proto+query): X[b][640][196] fp32 ->
// XT[row][640] bf16 (k contiguous) with the 3-bit swizzle baked per 16B unit
// within each 8-unit (64-elem) K-group: stored_unit = (u&8)|((u&7)^(row&7)),
// plus fp32 norms.  vs old prep: 64-wide i-slabs (4 blocks/batch instead of
// 13), phase-1 reads 256 B CONTIGUOUS per c-row (16 lanes x float4), 4x fewer
// blocks / syncthreads, one launch instead of two.
// grid = (4, 310): y<300 -> query, else proto.  i0 = x*64; block 3 covers
// only i 192..195 (masked, mostly idle but tiny).
// ---------------------------------------------------------------------------
__global__ __launch_bounds__(256)
void prep_all(const float* __restrict__ proto, const float* __restrict__ query,
              uint4* __restrict__ pT, uint4* __restrict__ qT,
              float* __restrict__ pn, float* __restrict__ qn)
{
    __shared__ float T[128][65];     // 33.3 KB, odd stride vs banks
    __shared__ float ssL[64][17];    // 4.4 KB

    const int bi = blockIdx.y;
    const bool isQ = (bi < QN);
    const int b  = isQ ? bi : bi - QN;
    const float* Xb = (isQ ? query : proto) + (size_t)b * (CD * IJ);
    uint4* XT   = isQ ? qT : pT;
    float* nrm  = isQ ? qn : pn;
    const int rowbase = b * IJ;

    const int i0 = blockIdx.x * 64;
    const int t  = threadIdx.x;

    // phase-1 identity: 16 c-rows x 16 lanes(i-quads) per pass
    const int cg = t >> 4;               // c within pass: 0..15
    const int i4 = (t & 15) * 4;         // 0..60
    const int iv = i0 + i4;
    const bool liv = (iv <= IJ - 4);     // full float4 in range

    // phase-2 identity: unit u = t&15, i-rows ilb..ilb+3
    const int u   = t & 15;
    const int ilb = (t >> 4) * 4;

    float ss[4] = {0.f, 0.f, 0.f, 0.f};

    for (int cc = 0; cc < CD / 128; ++cc) {
        // ---- phase 1: stage 128 c-rows x 64 i into T (8 passes, no sync
        // between passes: distinct rows)
        #pragma unroll
        for (int pass = 0; pass < 8; ++pass) {
            int cl = pass * 16 + cg;
            int c  = cc * 128 + cl;
            float4 v = make_float4(0.f, 0.f, 0.f, 0.f);
            if (liv) v = *(const float4*)&Xb[(size_t)c * IJ + iv];
            T[cl][i4 + 0] = v.x; T[cl][i4 + 1] = v.y;
            T[cl][i4 + 2] = v.z; T[cl][i4 + 3] = v.w;
        }
        __syncthreads();
        // ---- phase 2: transpose-out 4 i-rows per thread, unit u
        #pragma unroll
        for (int j = 0; j < 4; ++j) {
            int il = ilb + j;
            float v[8];
            #pragma unroll
            for (int r = 0; r < 8; ++r) { v[r] = T[u * 8 + r][il]; ss[j] += v[r] * v[r]; }
            int ig = i0 + il;
            if (ig < IJ) {
                union { unsigned short s[8]; uint4 q; } pk;
                #pragma unroll
                for (int r = 0; r < 8; ++r) pk.s[r] = f2bf(v[r]);
                int rowg = rowbase + ig;
                int us = (u & 8) | ((u & 7) ^ (rowg & 7));
                XT[(size_t)rowg * (CD / 8) + cc * 16 + us] = pk.q;
            }
        }
        __syncthreads();
    }

    #pragma unroll
    for (int j = 0; j < 4; ++j) ssL[ilb + j][u] = ss[j];
    __syncthreads();
    if (t < 64) {
        int ig = i0 + t;
        if (ig < IJ) {
            float s = 0.f;
            #pragma unroll
            for (int k = 0; k < 16; ++k) s += ssL[t][k];
            nrm[rowbase + ig] = sqrtf(s);
        }
    }
}

// ---------------------------------------------------------------------------
// GEMM (VERBATIM round-8 best: 275 us, MfmaUtil 23.5%, 0 bank conflicts).
// C[m][n] = sum_c AT[m][c]*BT[n][c].  256x256 tile, BK=64, 8 waves (2M x 4N),
// per-wave 128x64 (acc[8][4] of 16x16x32).  8-phase / 2-K-tiles-per-iter,
// counted vmcnt (VMC(2) gates only, never 0 in loop), leading-only barriers
// on non-gate phases, swapped-operand MFMA -> float4 epilogue stores.
// ---------------------------------------------------------------------------
__global__ __launch_bounds__(512, 2)
void gemm_kernel(const uint4* __restrict__ AT, const uint4* __restrict__ BT,
                 const float* __restrict__ pn, const float* __restrict__ qn,
                 float* __restrict__ out)
{
    __shared__ unsigned short lds[2 * BUFE];   // 128 KB

    const int bid = blockIdx.x;
    const int swz = (bid & 7) * CPX + (bid >> 3);   // bijective (1840%8==0)
    const int mt  = swz & (MT_TILES - 1);
    const int nt  = swz >> 3;
    const int m0  = mt * BM;
    const int n0  = nt * BN;

    const int t  = threadIdx.x;
    const int w  = t >> 6, l = t & 63;
    const int fr = l & 15, fq = l >> 4;
    const int wm0 = (w >> 2) * 128;   // 2 M-waves
    const int wn0 = (w & 3) * 64;     // 4 N-waves

    const int lr = l >> 3, lu = l & 7;
    int ra00 = m0 +   0 + w * 8 + lr; if (ra00 > MROWS - 1) ra00 = MROWS - 1;
    int ra01 = m0 +  64 + w * 8 + lr; if (ra01 > MROWS - 1) ra01 = MROWS - 1;
    int ra10 = m0 + 128 + w * 8 + lr; if (ra10 > MROWS - 1) ra10 = MROWS - 1;
    int ra11 = m0 + 192 + w * 8 + lr; if (ra11 > MROWS - 1) ra11 = MROWS - 1;
    int rb00 = n0 +   0 + w * 8 + lr; if (rb00 > NTOT - 1) rb00 = NTOT - 1;
    int rb01 = n0 +  64 + w * 8 + lr; if (rb01 > NTOT - 1) rb01 = NTOT - 1;
    int rb10 = n0 + 128 + w * 8 + lr; if (rb10 > NTOT - 1) rb10 = NTOT - 1;
    int rb11 = n0 + 192 + w * 8 + lr; if (rb11 > NTOT - 1) rb11 = NTOT - 1;
    const uint4* ga00 = AT + (size_t)ra00 * 80 + lu;
    const uint4* ga01 = AT + (size_t)ra01 * 80 + lu;
    const uint4* ga10 = AT + (size_t)ra10 * 80 + lu;
    const uint4* ga11 = AT + (size_t)ra11 * 80 + lu;
    const uint4* gb00 = BT + (size_t)rb00 * 80 + lu;
    const uint4* gb01 = BT + (size_t)rb01 * 80 + lu;
    const uint4* gb10 = BT + (size_t)rb10 * 80 + lu;
    const uint4* gb11 = BT + (size_t)rb11 * 80 + lu;
    const int la00 = (  0 + w * 8) * 64;
    const int la01 = ( 64 + w * 8) * 64;
    const int la10 = (128 + w * 8) * 64;
    const int la11 = (192 + w * 8) * 64;
    const int lb00 = BM * 64 + (  0 + w * 8) * 64;
    const int lb01 = BM * 64 + ( 64 + w * 8) * 64;
    const int lb10 = BM * 64 + (128 + w * 8) * 64;
    const int lb11 = BM * 64 + (192 + w * 8) * 64;

    const int fqS0 = fq << 3;
    const int fqS1 = (fq + 4) << 3;
    int baA[8], kyA[8], baB[4], kyB[4];
    #pragma unroll
    for (int i = 0; i < 8; ++i) {
        int rowa = wm0 + i * 16 + fr;
        baA[i] = rowa * 64;  kyA[i] = (rowa & 7) << 3;
    }
    #pragma unroll
    for (int i = 0; i < 4; ++i) {
        int rowb = wn0 + i * 16 + fr;
        baB[i] = BM * 64 + rowb * 64;  kyB[i] = (rowb & 7) << 3;
    }

    f32x4 acc[8][4];
    #pragma unroll
    for (int a = 0; a < 8; ++a)
        #pragma unroll
        for (int bb = 0; bb < 4; ++bb)
            acc[a][bb] = (f32x4){0.f, 0.f, 0.f, 0.f};

#define ST2(PA, PB, LA, LB)                                               \
    gload16(PA, (char*)&lds[(LA)]); PA += 8;                              \
    gload16(PB, (char*)&lds[(LB)]); PB += 8;

#define RD_A(OC, G)                                                       \
    _Pragma("unroll")                                                     \
    for (int mm = 0; mm < 4; ++mm) {                                      \
        af[mm]   = *(const bf16x8*)&lds[(OC) + baA[(G)+mm]                \
                                        + (fqS0 ^ kyA[(G)+mm])];          \
        af[4+mm] = *(const bf16x8*)&lds[(OC) + baA[(G)+mm]                \
                                        + (fqS1 ^ kyA[(G)+mm])];          \
    }
#define RD_B(BV, OC, G)                                                   \
    _Pragma("unroll")                                                     \
    for (int nn = 0; nn < 2; ++nn) {                                      \
        BV[nn]   = *(const bf16x8*)&lds[(OC) + baB[(G)+nn]                \
                                        + (fqS0 ^ kyB[(G)+nn])];          \
        BV[2+nn] = *(const bf16x8*)&lds[(OC) + baB[(G)+nn]                \
                                        + (fqS1 ^ kyB[(G)+nn])];          \
    }
#define MF(MB, NB, BV)                                                    \
    _Pragma("unroll")                                                     \
    for (int ks = 0; ks < 2; ++ks)                                        \
        _Pragma("unroll")                                                 \
        for (int mm = 0; mm < 4; ++mm)                                    \
            _Pragma("unroll")                                             \
            for (int nn = 0; nn < 2; ++nn)                                \
                acc[(MB)+mm][(NB)+nn] =                                   \
                    __builtin_amdgcn_mfma_f32_16x16x32_bf16(              \
                        BV[ks*2+nn], af[ks*4+mm],                         \
                        acc[(MB)+mm][(NB)+nn], 0, 0, 0);

#define BAR    __builtin_amdgcn_s_barrier()
#define LGKM0  do { asm volatile("s_waitcnt lgkmcnt(0)" ::: "memory");    \
                    __builtin_amdgcn_sched_barrier(0); } while (0)
#define VMC(N) asm volatile("s_waitcnt vmcnt(" #N ")" ::: "memory")
#define PRIO1  __builtin_amdgcn_s_setprio(1)
#define PRIO0  __builtin_amdgcn_s_setprio(0)

    ST2(ga00, ga01, la00, la01);               // t0 A0
    ST2(gb00, gb01, lb00, lb01);               // t0 B0
    ST2(ga10, ga11, la10, la11);               // t0 A1
    ST2(gb10, gb11, lb10, lb11);               // t0 B1
    ST2(ga00, ga01, BUFE + la00, BUFE + la01); // t1 A0
    VMC(2); BAR;

    for (int i5 = 0; i5 < NTK / 2; ++i5) {
        bf16x8 af[8], b0[4], b1[4];
        // P1
        RD_A(0, 0); RD_B(b0, 0, 0);
        ST2(gb00, gb01, BUFE + lb00, BUFE + lb01);
        BAR; LGKM0;
        PRIO1; MF(0, 0, b0); PRIO0;
        // P2
        RD_B(b1, 0, 2);
        ST2(ga10, ga11, BUFE + la10, BUFE + la11);
        BAR; LGKM0;
        PRIO1; MF(0, 2, b1); PRIO0;
        // P3
        RD_A(0, 4);
        ST2(gb10, gb11, BUFE + lb10, BUFE + lb11);
        BAR; LGKM0;
        PRIO1; MF(4, 2, b1); PRIO0;
        // P4 (gate)
        ST2(ga00, ga01, la00, la01);
        PRIO1; MF(4, 0, b0); PRIO0;
        VMC(2); BAR;
        // P5
        RD_A(BUFE, 0); RD_B(b0, BUFE, 0);
        ST2(gb00, gb01, lb00, lb01);
        BAR; LGKM0;
        PRIO1; MF(0, 0, b0); PRIO0;
        // P6
        RD_B(b1, BUFE, 2);
        ST2(ga10, ga11, la10, la11);
        BAR; LGKM0;
        PRIO1; MF(0, 2, b1); PRIO0;
        // P7
        RD_A(BUFE, 4);
        ST2(gb10, gb11, lb10, lb11);
        BAR; LGKM0;
        PRIO1; MF(4, 2, b1); PRIO0;
        // P8 (gate)
        ST2(ga00, ga01, BUFE + la00, BUFE + la01);
        PRIO1; MF(4, 0, b0); PRIO0;
        VMC(2); BAR;
    }

    VMC(0);   // drain tail garbage loads before epilogue

#undef ST2
#undef RD_A
#undef RD_B
#undef MF
#undef BAR
#undef LGKM0
#undef VMC
#undef PRIO1
#undef PRIO0

    float4 rqv4[4];
    int    nok[4];
    size_t ob[4];
    #pragma unroll
    for (int tn = 0; tn < 4; ++tn) {
        int n = n0 + wn0 + tn * 16 + fq * 4;
        nok[tn] = (n < NTOT);
        int nc = nok[tn] ? n : NTOT - 4;
        int q  = nc / IJ;
        int j  = nc - q * IJ;
        rqv4[tn] = *(const float4*)&qn[nc];
        ob[tn] = (size_t)q * OUTQ + j;
    }
    #pragma unroll
    for (int tm = 0; tm < 8; ++tm) {
        int m = m0 + wm0 + tm * 16 + fr;
        if (m < MROWS) {
            float rp = pn[m];
            #pragma unroll
            for (int tn = 0; tn < 4; ++tn) {
                if (nok[tn]) {
                    f32x4 a = acc[tm][tn];
                    float4 o;
                    o.x = a[0] * __builtin_amdgcn_rcpf(fmaxf(rp * rqv4[tn].x, EPSV));
                    o.y = a[1] * __builtin_amdgcn_rcpf(fmaxf(rp * rqv4[tn].y, EPSV));
                    o.z = a[2] * __builtin_amdgcn_rcpf(fmaxf(rp * rqv4[tn].z, EPSV));
                    o.w = a[3] * __builtin_amdgcn_rcpf(fmaxf(rp * rqv4[tn].w, EPSV));
                    *(float4*)&out[ob[tn] + (size_t)m * IJ] = o;
                }
            }
        }
    }
}

// ---------------------------------------------------------------------------
// Fallback (round-1 kernel, known-passing) if ws_size is insufficient.
// ---------------------------------------------------------------------------
#define BMF 128
#define BNF 224
#define LPAD 40
__global__ __launch_bounds__(512, 4)
void sim_fallback(const float* __restrict__ proto,
                  const float* __restrict__ query,
                  float* __restrict__ out)
{
    __shared__ unsigned short As[BMF][LPAD];
    __shared__ unsigned short Bs[BNF][LPAD];
    __shared__ float redA[4][BMF];
    __shared__ float redB[2][BNF];
    __shared__ float rpS[BMF];
    __shared__ float rqS[BNF];

    const int tid = threadIdx.x;
    const int m0  = blockIdx.x * BMF;
    const int q   = blockIdx.y;

    const int mA  = tid & (BMF - 1);
    const int krA = tid >> 7;
    const int wiA = m0 + mA;
    const bool va = (wiA < MROWS);
    const int wA  = va ? (wiA / IJ) : 0;
    const int iA  = va ? (wiA - wA * IJ) : 0;
    const float* pA = proto + wA * (CD * IJ) + iA;

    const bool tb  = (tid < 448);
    const int jB   = tb ? (tid % BNF) : 0;
    const int krB  = tb ? (tid / BNF) : 0;
    const bool vb  = tb && (jB < IJ);
    const float* qB = query + q * (CD * IJ) + jB;

    float ssA = 0.f, ssB = 0.f;

    const int wv   = tid >> 6;
    const int lane = tid & 63;
    const int wm0  = (wv >> 1) * 32;
    const int wn0  = (wv & 1) * 112;
    const int fr   = lane & 15;
    const int fq   = lane >> 4;

    f32x4 acc[2][7];
    #pragma unroll
    for (int a = 0; a < 2; a++)
        #pragma unroll
        for (int b = 0; b < 7; b++)
            acc[a][b] = (f32x4){0.f, 0.f, 0.f, 0.f};

    for (int it = 0; it < CD / 32; ++it) {
        const int c0 = it * 32;
        {
            float v[8];
            #pragma unroll
            for (int e = 0; e < 8; e++) {
                int c = c0 + krA * 8 + e;
                v[e] = va ? pA[c * IJ] : 0.f;
            }
            #pragma unroll
            for (int e = 0; e < 8; e++) ssA += v[e] * v[e];
            union { unsigned short s[8]; uint4 u; } pk;
            #pragma unroll
            for (int e = 0; e < 8; e++) pk.s[e] = f2bf(v[e]);
            *(uint4*)&As[mA][krA * 8] = pk.u;
        }
        if (tb) {
            #pragma unroll
            for (int h = 0; h < 2; ++h) {
                float v[8];
                #pragma unroll
                for (int e = 0; e < 8; e++) {
                    int c = c0 + krB * 16 + h * 8 + e;
                    v[e] = vb ? qB[c * IJ] : 0.f;
                }
                #pragma unroll
                for (int e = 0; e < 8; e++) ssB += v[e] * v[e];
                union { unsigned short s[8]; uint4 u; } pk;
                #pragma unroll
                for (int e = 0; e < 8; e++) pk.s[e] = f2bf(v[e]);
                *(uint4*)&Bs[jB][krB * 16 + h * 8] = pk.u;
            }
        }
        __syncthreads();
        bf16x8 af[2], bfv[7];
        #pragma unroll
        for (int tm = 0; tm < 2; tm++)
            af[tm] = *(const bf16x8*)&As[wm0 + tm * 16 + fr][fq * 8];
        #pragma unroll
        for (int tn = 0; tn < 7; tn++)
            bfv[tn] = *(const bf16x8*)&Bs[wn0 + tn * 16 + fr][fq * 8];
        #pragma unroll
        for (int tm = 0; tm < 2; tm++)
            #pragma unroll
            for (int tn = 0; tn < 7; tn++)
                acc[tm][tn] = __builtin_amdgcn_mfma_f32_16x16x32_bf16(
                    af[tm], bfv[tn], acc[tm][tn], 0, 0, 0);
        __syncthreads();
    }

    redA[krA][mA] = ssA;
    if (tb) redB[krB][jB] = ssB;
    __syncthreads();
    if (tid < BMF) {
        rpS[tid] = sqrtf(redA[0][tid] + redA[1][tid] + redA[2][tid] + redA[3][tid]);
    } else if (tid >= 256 && tid < 256 + BNF) {
        int j = tid - 256;
        rqS[j] = sqrtf(redB[0][j] + redB[1][j]);
    }
    __syncthreads();

    #pragma unroll
    for (int tm = 0; tm < 2; tm++) {
        #pragma unroll
        for (int tn = 0; tn < 7; tn++) {
            #pragma unroll
            for (int r = 0; r < 4; r++) {
                int rl = wm0 + tm * 16 + fq * 4 + r;
                int cl = wn0 + tn * 16 + fr;
                int wi = m0 + rl;
                if (wi < MROWS && cl < IJ) {
                    float denom = fmaxf(rpS[rl] * rqS[cl], 1e-8f);
                    out[(size_t)(q * MROWS + wi) * IJ + cl] = acc[tm][tn][r] / denom;
                }
            }
        }
    }
}

// ---------------------------------------------------------------------------
extern "C" void kernel_launch(void* const* d_in, const int* in_sizes, int n_in,
                              void* d_out, int out_size, void* d_ws, size_t ws_size,
                              hipStream_t stream) {
    const float* proto = (const float*)d_in[0];
    const float* query = (const float*)d_in[1];
    float* out = (float*)d_out;

    // workspace layout
    const size_t off_pT = 0;                       // 1960*640*2 = 2,508,800
    const size_t off_qT = 2508800;                 // 58800*640*2 = 75,264,000
    const size_t off_pn = 77772800;                // 1960*4
    const size_t off_qn = 77780736;                // 58800*4
    const size_t need   = 78015936;

    if (ws_size < need) {
        dim3 grid((MROWS + BMF - 1) / BMF, QN);
        sim_fallback<<<grid, 512, 0, stream>>>(proto, query, out);
        return;
    }

    char* ws = (char*)d_ws;
    uint4* pT = (uint4*)(ws + off_pT);
    uint4* qT = (uint4*)(ws + off_qT);
    float* pn = (float*)(ws + off_pn);
    float* qn = (float*)(ws + off_qn);

    prep_all<<<dim3(4, QN + WN), 256, 0, stream>>>(proto, query, pT, qT, pn, qn);

    gemm_kernel<<<dim3(NWG), 512, 0, stream>>>(pT, qT, pn, qn, out);
}